// Round 1
// baseline (1538.333 us; speedup 1.0000x reference)
//
#include <hip/hip_runtime.h>

// HierarchicalStaticNeuralTexture:
//   uv_inputs: [1, 2, 1024, 1024] f32, coords in [-1,1]
//   data:      [1, 16, 2048, 1024] f32  (4 mip levels stacked in Y:
//              level l: rows offY..offY+W, cols 0..W, W = 1024>>l,
//              offY = 0,1024,1536,1792)
//   out:       [1, 16, 1024, 1024] f32 = sum over levels of bilinear
//              grid_sample (border padding, align_corners=False)

#define IMG 1024
#define NCH 16
#define DATA_ROWSTRIDE 1024
#define DATA_CHSTRIDE (2048 * 1024)

__global__ __launch_bounds__(256) void hsnt_kernel(
    const float* __restrict__ uv,
    const float* __restrict__ data,
    float* __restrict__ out)
{
    const int idx = blockIdx.x * blockDim.x + threadIdx.x;
    if (idx >= IMG * IMG) return;

    const float gx = uv[idx];
    const float gy = uv[IMG * IMG + idx];

    float acc[NCH];
#pragma unroll
    for (int c = 0; c < NCH; ++c) acc[c] = 0.0f;

    int offY = 0;
    int W = 1024;

#pragma unroll
    for (int l = 0; l < 4; ++l) {
        const float Wf = (float)W;
        // x = clip(((gx+1)*W - 1)*0.5, 0, W-1)
        float x = fminf(fmaxf(fmaf(gx + 1.0f, Wf * 0.5f, -0.5f), 0.0f), Wf - 1.0f);
        float y = fminf(fmaxf(fmaf(gy + 1.0f, Wf * 0.5f, -0.5f), 0.0f), Wf - 1.0f);

        const float x0f = floorf(x);
        const float y0f = floorf(y);
        const float wx = x - x0f;
        const float wy = y - y0f;
        const int x0 = (int)x0f;
        const int y0 = (int)y0f;
        const int x1 = min(x0 + 1, W - 1);
        const int y1 = min(y0 + 1, W - 1);

        const float w11 = wx * wy;
        const float w10 = wy - w11;          // (1-wx)*wy
        const float w01 = wx - w11;          // wx*(1-wy)
        const float w00 = 1.0f - wx - wy + w11;  // (1-wx)*(1-wy)

        const int r0 = offY + y0;
        const int r1 = offY + y1;

        const float* p00 = data + (size_t)r0 * DATA_ROWSTRIDE + x0;
        const float* p01 = data + (size_t)r0 * DATA_ROWSTRIDE + x1;
        const float* p10 = data + (size_t)r1 * DATA_ROWSTRIDE + x0;
        const float* p11 = data + (size_t)r1 * DATA_ROWSTRIDE + x1;

#pragma unroll
        for (int c = 0; c < NCH; ++c) {
            const size_t co = (size_t)c * DATA_CHSTRIDE;
            const float t00 = p00[co];
            const float t01 = p01[co];
            const float t10 = p10[co];
            const float t11 = p11[co];
            acc[c] = fmaf(t00, w00,
                     fmaf(t01, w01,
                     fmaf(t10, w10,
                     fmaf(t11, w11, acc[c]))));
        }

        offY += W;
        W >>= 1;
    }

#pragma unroll
    for (int c = 0; c < NCH; ++c) {
        out[(size_t)c * (IMG * IMG) + idx] = acc[c];
    }
}

extern "C" void kernel_launch(void* const* d_in, const int* in_sizes, int n_in,
                              void* d_out, int out_size, void* d_ws, size_t ws_size,
                              hipStream_t stream) {
    const float* uv   = (const float*)d_in[0];   // [1,2,1024,1024]
    const float* data = (const float*)d_in[1];   // [1,16,2048,1024]
    float* out = (float*)d_out;                  // [1,16,1024,1024]

    const int npix = IMG * IMG;
    const int block = 256;
    const int grid = (npix + block - 1) / block;
    hsnt_kernel<<<grid, block, 0, stream>>>(uv, data, out);
}

// Round 2
// 267.539 us; speedup vs baseline: 5.7499x; 5.7499x over previous
//
#include <hip/hip_runtime.h>

// HierarchicalStaticNeuralTexture:
//   uv_inputs: [1, 2, 1024, 1024] f32, coords in [-1,1]
//   data:      [1, 16, 2048, 1024] f32  (4 mip levels stacked in Y)
//   out:       [1, 16, 1024, 1024] f32 = sum over 4 levels of bilinear
//              grid_sample (border padding, align_corners=False)
//
// Round 2: channel-major -> texel-major transpose into d_ws so each corner
// texel (16 ch) is one contiguous 64B cache line. Levels compacted:
//   level l: W = 1024>>l, base texel offset BASE[l], source row offY[l].

#define IMG 1024
#define NCH 16
#define DATA_ROWSTRIDE 1024
#define DATA_CHSTRIDE (2048 * 1024)

// Compact texel-major layout (texel index -> 16 floats)
#define L0_BASE 0
#define L1_BASE 1048576          // 1024*1024
#define L2_BASE 1310720          // + 512*512
#define L3_BASE 1376256          // + 256*256
#define TOT_TEXELS 1392640       // + 128*128
#define WS_NEEDED ((size_t)TOT_TEXELS * NCH * sizeof(float))   // 89,128,960 B

// ---------------- transpose: data[c][y][x] -> tex[(base+t)*16 + c] -----------
__global__ __launch_bounds__(256) void hsnt_transpose(
    const float* __restrict__ data, float* __restrict__ tex)
{
    int b = blockIdx.x;
    int base, offY, logW;
    if (b < 4096)      { base = L0_BASE; offY = 0;    logW = 10; }
    else if (b < 5120) { base = L1_BASE; offY = 1024; logW = 9;  b -= 4096; }
    else if (b < 5376) { base = L2_BASE; offY = 1536; logW = 8;  b -= 5120; }
    else               { base = L3_BASE; offY = 1792; logW = 7;  b -= 5376; }

    const int t = b * 256 + threadIdx.x;        // level-linear texel index
    const int y = t >> logW;
    const int x = t & ((1 << logW) - 1);

    const float* src = data + (size_t)(offY + y) * DATA_ROWSTRIDE + x;
    float v[NCH];
#pragma unroll
    for (int c = 0; c < NCH; ++c)
        v[c] = src[(size_t)c * DATA_CHSTRIDE];   // coalesced across threads per c

    float4* dst = (float4*)(tex + ((size_t)(base + t) << 4));
    dst[0] = make_float4(v[0],  v[1],  v[2],  v[3]);
    dst[1] = make_float4(v[4],  v[5],  v[6],  v[7]);
    dst[2] = make_float4(v[8],  v[9],  v[10], v[11]);
    dst[3] = make_float4(v[12], v[13], v[14], v[15]);
}

// ---------------- sampling from texel-major layout ---------------------------
__device__ __forceinline__ void fma4(float4& a, const float4 t, const float w) {
    a.x = fmaf(t.x, w, a.x);
    a.y = fmaf(t.y, w, a.y);
    a.z = fmaf(t.z, w, a.z);
    a.w = fmaf(t.w, w, a.w);
}

__global__ __launch_bounds__(256) void hsnt_sample(
    const float* __restrict__ uv,
    const float* __restrict__ tex,
    float* __restrict__ out)
{
    const int idx = blockIdx.x * blockDim.x + threadIdx.x;
    if (idx >= IMG * IMG) return;

    const float gx = uv[idx];
    const float gy = uv[IMG * IMG + idx];

    float4 a0 = make_float4(0.f, 0.f, 0.f, 0.f);
    float4 a1 = a0, a2 = a0, a3 = a0;

    const int   BASE[4] = { L0_BASE, L1_BASE, L2_BASE, L3_BASE };

#pragma unroll
    for (int l = 0; l < 4; ++l) {
        const int   W  = 1024 >> l;
        const float Wf = (float)W;

        float x = fminf(fmaxf(fmaf(gx + 1.0f, Wf * 0.5f, -0.5f), 0.0f), Wf - 1.0f);
        float y = fminf(fmaxf(fmaf(gy + 1.0f, Wf * 0.5f, -0.5f), 0.0f), Wf - 1.0f);

        const float x0f = floorf(x);
        const float y0f = floorf(y);
        const float wx = x - x0f;
        const float wy = y - y0f;
        const int x0 = (int)x0f;
        const int y0 = (int)y0f;
        const int x1 = min(x0 + 1, W - 1);
        const int y1 = min(y0 + 1, W - 1);

        const float w11 = wx * wy;
        const float w10 = wy - w11;             // (1-wx)*wy
        const float w01 = wx - w11;             // wx*(1-wy)
        const float w00 = 1.0f - wx - wy + w11; // (1-wx)*(1-wy)

        const int r0 = BASE[l] + y0 * W;
        const int r1 = BASE[l] + y1 * W;

        const float4* t00 = (const float4*)(tex + ((size_t)(r0 + x0) << 4));
        const float4* t01 = (const float4*)(tex + ((size_t)(r0 + x1) << 4));
        const float4* t10 = (const float4*)(tex + ((size_t)(r1 + x0) << 4));
        const float4* t11 = (const float4*)(tex + ((size_t)(r1 + x1) << 4));

        fma4(a0, t00[0], w00); fma4(a1, t00[1], w00);
        fma4(a2, t00[2], w00); fma4(a3, t00[3], w00);

        fma4(a0, t01[0], w01); fma4(a1, t01[1], w01);
        fma4(a2, t01[2], w01); fma4(a3, t01[3], w01);

        fma4(a0, t10[0], w10); fma4(a1, t10[1], w10);
        fma4(a2, t10[2], w10); fma4(a3, t10[3], w10);

        fma4(a0, t11[0], w11); fma4(a1, t11[1], w11);
        fma4(a2, t11[2], w11); fma4(a3, t11[3], w11);
    }

    const float acc[NCH] = { a0.x, a0.y, a0.z, a0.w,
                             a1.x, a1.y, a1.z, a1.w,
                             a2.x, a2.y, a2.z, a2.w,
                             a3.x, a3.y, a3.z, a3.w };
#pragma unroll
    for (int c = 0; c < NCH; ++c)
        out[(size_t)c * (IMG * IMG) + idx] = acc[c];
}

// ---------------- fallback (round-1 naive, if ws too small) ------------------
__global__ __launch_bounds__(256) void hsnt_naive(
    const float* __restrict__ uv,
    const float* __restrict__ data,
    float* __restrict__ out)
{
    const int idx = blockIdx.x * blockDim.x + threadIdx.x;
    if (idx >= IMG * IMG) return;

    const float gx = uv[idx];
    const float gy = uv[IMG * IMG + idx];

    float acc[NCH];
#pragma unroll
    for (int c = 0; c < NCH; ++c) acc[c] = 0.0f;

    int offY = 0;
    int W = 1024;
#pragma unroll
    for (int l = 0; l < 4; ++l) {
        const float Wf = (float)W;
        float x = fminf(fmaxf(fmaf(gx + 1.0f, Wf * 0.5f, -0.5f), 0.0f), Wf - 1.0f);
        float y = fminf(fmaxf(fmaf(gy + 1.0f, Wf * 0.5f, -0.5f), 0.0f), Wf - 1.0f);
        const float x0f = floorf(x);
        const float y0f = floorf(y);
        const float wx = x - x0f;
        const float wy = y - y0f;
        const int x0 = (int)x0f;
        const int y0 = (int)y0f;
        const int x1 = min(x0 + 1, W - 1);
        const int y1 = min(y0 + 1, W - 1);
        const float w11 = wx * wy;
        const float w10 = wy - w11;
        const float w01 = wx - w11;
        const float w00 = 1.0f - wx - wy + w11;
        const int r0 = offY + y0;
        const int r1 = offY + y1;
        const float* p00 = data + (size_t)r0 * DATA_ROWSTRIDE + x0;
        const float* p01 = data + (size_t)r0 * DATA_ROWSTRIDE + x1;
        const float* p10 = data + (size_t)r1 * DATA_ROWSTRIDE + x0;
        const float* p11 = data + (size_t)r1 * DATA_ROWSTRIDE + x1;
#pragma unroll
        for (int c = 0; c < NCH; ++c) {
            const size_t co = (size_t)c * DATA_CHSTRIDE;
            acc[c] = fmaf(p00[co], w00,
                     fmaf(p01[co], w01,
                     fmaf(p10[co], w10,
                     fmaf(p11[co], w11, acc[c]))));
        }
        offY += W;
        W >>= 1;
    }
#pragma unroll
    for (int c = 0; c < NCH; ++c)
        out[(size_t)c * (IMG * IMG) + idx] = acc[c];
}

extern "C" void kernel_launch(void* const* d_in, const int* in_sizes, int n_in,
                              void* d_out, int out_size, void* d_ws, size_t ws_size,
                              hipStream_t stream) {
    const float* uv   = (const float*)d_in[0];   // [1,2,1024,1024]
    const float* data = (const float*)d_in[1];   // [1,16,2048,1024]
    float* out = (float*)d_out;                  // [1,16,1024,1024]

    const int npix = IMG * IMG;
    const int block = 256;
    const int grid = (npix + block - 1) / block;

    if (ws_size >= WS_NEEDED && d_ws != nullptr) {
        float* tex = (float*)d_ws;
        hsnt_transpose<<<TOT_TEXELS / 256, 256, 0, stream>>>(data, tex);
        hsnt_sample<<<grid, block, 0, stream>>>(uv, tex, out);
    } else {
        hsnt_naive<<<grid, block, 0, stream>>>(uv, data, out);
    }
}

// Round 3
// 173.062 us; speedup vs baseline: 8.8889x; 1.5459x over previous
//
#include <hip/hip_runtime.h>
#include <hip/hip_fp16.h>

// HierarchicalStaticNeuralTexture:
//   uv_inputs: [1, 2, 1024, 1024] f32, coords in [-1,1]
//   data:      [1, 16, 2048, 1024] f32  (4 mip levels stacked in Y)
//   out:       [1, 16, 1024, 1024] f32 = sum over 4 levels of bilinear
//              grid_sample (border padding, align_corners=False)
//
// Round 3: texel-major atlas in fp16 — texel = 16ch x 2B = 32 B.
//   Halves miss bytes, halves lane-request count (2 dwordx4 per corner),
//   halves L2/L3 footprint (43 MB total, L0 = 32 MB).

#define IMG 1024
#define NCH 16
#define DATA_ROWSTRIDE 1024
#define DATA_CHSTRIDE (2048 * 1024)

// Compact texel-major layout (texel index -> 16 halves)
#define L0_BASE 0
#define L1_BASE 1048576          // 1024*1024
#define L2_BASE 1310720          // + 512*512
#define L3_BASE 1376256          // + 256*256
#define TOT_TEXELS 1392640       // + 128*128
#define WS_NEEDED ((size_t)TOT_TEXELS * NCH * sizeof(__half))  // 44.6 MB

// ---------------- transpose+quantize: data[c][y][x] -> tex16[(base+t)*16+c] --
__global__ __launch_bounds__(256) void hsnt_transpose_h(
    const float* __restrict__ data, __half* __restrict__ tex)
{
    int b = blockIdx.x;
    int base, offY, logW;
    if (b < 4096)      { base = L0_BASE; offY = 0;    logW = 10; }
    else if (b < 5120) { base = L1_BASE; offY = 1024; logW = 9;  b -= 4096; }
    else if (b < 5376) { base = L2_BASE; offY = 1536; logW = 8;  b -= 5120; }
    else               { base = L3_BASE; offY = 1792; logW = 7;  b -= 5376; }

    const int t = b * 256 + threadIdx.x;        // level-linear texel index
    const int y = t >> logW;
    const int x = t & ((1 << logW) - 1);

    const float* src = data + (size_t)(offY + y) * DATA_ROWSTRIDE + x;
    __half h[NCH];
#pragma unroll
    for (int c = 0; c < NCH; ++c)
        h[c] = __float2half(src[(size_t)c * DATA_CHSTRIDE]);  // coalesced per c

    uint4* dst = (uint4*)(tex + ((size_t)(base + t) << 4));
    dst[0] = *(const uint4*)&h[0];
    dst[1] = *(const uint4*)&h[8];
}

// ---------------- sampling from fp16 texel-major layout ----------------------
__device__ __forceinline__ void accum_texel(
    float* __restrict__ acc, const __half* __restrict__ tp, const float w)
{
    union U { uint4 u; __half2 h[4]; } a, b;
    a.u = *(const uint4*)tp;
    b.u = *(const uint4*)(tp + 8);
#pragma unroll
    for (int i = 0; i < 4; ++i) {
        const float2 f = __half22float2(a.h[i]);
        acc[2 * i]     = fmaf(f.x, w, acc[2 * i]);
        acc[2 * i + 1] = fmaf(f.y, w, acc[2 * i + 1]);
        const float2 g = __half22float2(b.h[i]);
        acc[8 + 2 * i]     = fmaf(g.x, w, acc[8 + 2 * i]);
        acc[8 + 2 * i + 1] = fmaf(g.y, w, acc[8 + 2 * i + 1]);
    }
}

__global__ __launch_bounds__(256) void hsnt_sample_h(
    const float* __restrict__ uv,
    const __half* __restrict__ tex,
    float* __restrict__ out)
{
    const int idx = blockIdx.x * blockDim.x + threadIdx.x;
    if (idx >= IMG * IMG) return;

    const float gx = uv[idx];
    const float gy = uv[IMG * IMG + idx];

    float acc[NCH];
#pragma unroll
    for (int c = 0; c < NCH; ++c) acc[c] = 0.0f;

    const int BASE[4] = { L0_BASE, L1_BASE, L2_BASE, L3_BASE };

#pragma unroll
    for (int l = 0; l < 4; ++l) {
        const int   W  = 1024 >> l;
        const float Wf = (float)W;

        float x = fminf(fmaxf(fmaf(gx + 1.0f, Wf * 0.5f, -0.5f), 0.0f), Wf - 1.0f);
        float y = fminf(fmaxf(fmaf(gy + 1.0f, Wf * 0.5f, -0.5f), 0.0f), Wf - 1.0f);

        const float x0f = floorf(x);
        const float y0f = floorf(y);
        const float wx = x - x0f;
        const float wy = y - y0f;
        const int x0 = (int)x0f;
        const int y0 = (int)y0f;
        const int x1 = min(x0 + 1, W - 1);
        const int y1 = min(y0 + 1, W - 1);

        const float w11 = wx * wy;
        const float w10 = wy - w11;             // (1-wx)*wy
        const float w01 = wx - w11;             // wx*(1-wy)
        const float w00 = 1.0f - wx - wy + w11; // (1-wx)*(1-wy)

        const int r0 = BASE[l] + y0 * W;
        const int r1 = BASE[l] + y1 * W;

        accum_texel(acc, tex + ((size_t)(r0 + x0) << 4), w00);
        accum_texel(acc, tex + ((size_t)(r0 + x1) << 4), w01);
        accum_texel(acc, tex + ((size_t)(r1 + x0) << 4), w10);
        accum_texel(acc, tex + ((size_t)(r1 + x1) << 4), w11);
    }

#pragma unroll
    for (int c = 0; c < NCH; ++c)
        out[(size_t)c * (IMG * IMG) + idx] = acc[c];
}

// ---------------- fallback (round-1 naive, if ws too small) ------------------
__global__ __launch_bounds__(256) void hsnt_naive(
    const float* __restrict__ uv,
    const float* __restrict__ data,
    float* __restrict__ out)
{
    const int idx = blockIdx.x * blockDim.x + threadIdx.x;
    if (idx >= IMG * IMG) return;

    const float gx = uv[idx];
    const float gy = uv[IMG * IMG + idx];

    float acc[NCH];
#pragma unroll
    for (int c = 0; c < NCH; ++c) acc[c] = 0.0f;

    int offY = 0;
    int W = 1024;
#pragma unroll
    for (int l = 0; l < 4; ++l) {
        const float Wf = (float)W;
        float x = fminf(fmaxf(fmaf(gx + 1.0f, Wf * 0.5f, -0.5f), 0.0f), Wf - 1.0f);
        float y = fminf(fmaxf(fmaf(gy + 1.0f, Wf * 0.5f, -0.5f), 0.0f), Wf - 1.0f);
        const float x0f = floorf(x);
        const float y0f = floorf(y);
        const float wx = x - x0f;
        const float wy = y - y0f;
        const int x0 = (int)x0f;
        const int y0 = (int)y0f;
        const int x1 = min(x0 + 1, W - 1);
        const int y1 = min(y0 + 1, W - 1);
        const float w11 = wx * wy;
        const float w10 = wy - w11;
        const float w01 = wx - w11;
        const float w00 = 1.0f - wx - wy + w11;
        const int r0 = offY + y0;
        const int r1 = offY + y1;
        const float* p00 = data + (size_t)r0 * DATA_ROWSTRIDE + x0;
        const float* p01 = data + (size_t)r0 * DATA_ROWSTRIDE + x1;
        const float* p10 = data + (size_t)r1 * DATA_ROWSTRIDE + x0;
        const float* p11 = data + (size_t)r1 * DATA_ROWSTRIDE + x1;
#pragma unroll
        for (int c = 0; c < NCH; ++c) {
            const size_t co = (size_t)c * DATA_CHSTRIDE;
            acc[c] = fmaf(p00[co], w00,
                     fmaf(p01[co], w01,
                     fmaf(p10[co], w10,
                     fmaf(p11[co], w11, acc[c]))));
        }
        offY += W;
        W >>= 1;
    }
#pragma unroll
    for (int c = 0; c < NCH; ++c)
        out[(size_t)c * (IMG * IMG) + idx] = acc[c];
}

extern "C" void kernel_launch(void* const* d_in, const int* in_sizes, int n_in,
                              void* d_out, int out_size, void* d_ws, size_t ws_size,
                              hipStream_t stream) {
    const float* uv   = (const float*)d_in[0];   // [1,2,1024,1024]
    const float* data = (const float*)d_in[1];   // [1,16,2048,1024]
    float* out = (float*)d_out;                  // [1,16,1024,1024]

    const int npix = IMG * IMG;
    const int block = 256;
    const int grid = (npix + block - 1) / block;

    if (ws_size >= WS_NEEDED && d_ws != nullptr) {
        __half* tex = (__half*)d_ws;
        hsnt_transpose_h<<<TOT_TEXELS / 256, 256, 0, stream>>>(data, tex);
        hsnt_sample_h<<<grid, block, 0, stream>>>(uv, tex, out);
    } else {
        hsnt_naive<<<grid, block, 0, stream>>>(uv, data, out);
    }
}

// Round 4
// 169.636 us; speedup vs baseline: 9.0684x; 1.0202x over previous
//
#include <hip/hip_runtime.h>
#include <hip/hip_fp16.h>

// HierarchicalStaticNeuralTexture:
//   uv_inputs: [1, 2, 1024, 1024] f32, coords in [-1,1]
//   data:      [1, 16, 2048, 1024] f32  (4 mip levels stacked in Y)
//   out:       [1, 16, 1024, 1024] f32 = sum over 4 levels of bilinear
//              grid_sample (border padding, align_corners=False)
//
// Round 4: MLP (memory-level-parallelism) restructure of the sampler.
//   fp16 texel-major atlas (32 B/texel) as in round 3; now the kernel
//   batches 2 levels at a time and issues all 16 dwordx4 corner loads
//   before accumulating, with __launch_bounds__(256,4) to allow ~128 VGPR.

#define IMG 1024
#define NCH 16
#define DATA_ROWSTRIDE 1024
#define DATA_CHSTRIDE (2048 * 1024)

// Compact texel-major layout (texel index -> 16 halves)
#define L0_BASE 0
#define L1_BASE 1048576          // 1024*1024
#define L2_BASE 1310720          // + 512*512
#define L3_BASE 1376256          // + 256*256
#define TOT_TEXELS 1392640       // + 128*128
#define WS_NEEDED ((size_t)TOT_TEXELS * NCH * sizeof(__half))  // 44.6 MB

// ---------------- transpose+quantize: data[c][y][x] -> tex16[(base+t)*16+c] --
__global__ __launch_bounds__(256) void hsnt_transpose_h(
    const float* __restrict__ data, __half* __restrict__ tex)
{
    int b = blockIdx.x;
    int base, offY, logW;
    if (b < 4096)      { base = L0_BASE; offY = 0;    logW = 10; }
    else if (b < 5120) { base = L1_BASE; offY = 1024; logW = 9;  b -= 4096; }
    else if (b < 5376) { base = L2_BASE; offY = 1536; logW = 8;  b -= 5120; }
    else               { base = L3_BASE; offY = 1792; logW = 7;  b -= 5376; }

    const int t = b * 256 + threadIdx.x;        // level-linear texel index
    const int y = t >> logW;
    const int x = t & ((1 << logW) - 1);

    const float* src = data + (size_t)(offY + y) * DATA_ROWSTRIDE + x;
    __half h[NCH];
#pragma unroll
    for (int c = 0; c < NCH; ++c)
        h[c] = __float2half(src[(size_t)c * DATA_CHSTRIDE]);  // coalesced per c

    uint4* dst = (uint4*)(tex + ((size_t)(base + t) << 4));
    dst[0] = *(const uint4*)&h[0];
    dst[1] = *(const uint4*)&h[8];
}

// ---------------- sampling: 2-level batches, 16 loads in flight --------------
__device__ __forceinline__ void accum_pair(
    float* __restrict__ acc, const uint4 lo, const uint4 hi, const float w)
{
    union U { uint4 u; __half2 h[4]; } a, b;
    a.u = lo;
    b.u = hi;
#pragma unroll
    for (int i = 0; i < 4; ++i) {
        const float2 f = __half22float2(a.h[i]);
        acc[2 * i]     = fmaf(f.x, w, acc[2 * i]);
        acc[2 * i + 1] = fmaf(f.y, w, acc[2 * i + 1]);
        const float2 g = __half22float2(b.h[i]);
        acc[8 + 2 * i]     = fmaf(g.x, w, acc[8 + 2 * i]);
        acc[8 + 2 * i + 1] = fmaf(g.y, w, acc[8 + 2 * i + 1]);
    }
}

__global__ __launch_bounds__(256, 4) void hsnt_sample_h(
    const float* __restrict__ uv,
    const __half* __restrict__ tex,
    float* __restrict__ out)
{
    const int idx = blockIdx.x * blockDim.x + threadIdx.x;
    if (idx >= IMG * IMG) return;

    const float gx = uv[idx];
    const float gy = uv[IMG * IMG + idx];

    float acc[NCH];
#pragma unroll
    for (int c = 0; c < NCH; ++c) acc[c] = 0.0f;

    const int BASE[4] = { L0_BASE, L1_BASE, L2_BASE, L3_BASE };

#pragma unroll
    for (int b = 0; b < 2; ++b) {
        int   off[8];
        float wgt[8];

        // address + weight setup for levels 2b and 2b+1
#pragma unroll
        for (int s = 0; s < 2; ++s) {
            const int   l  = 2 * b + s;
            const int   W  = 1024 >> l;
            const float Wf = (float)W;

            float x = fminf(fmaxf(fmaf(gx + 1.0f, Wf * 0.5f, -0.5f), 0.0f), Wf - 1.0f);
            float y = fminf(fmaxf(fmaf(gy + 1.0f, Wf * 0.5f, -0.5f), 0.0f), Wf - 1.0f);

            const float x0f = floorf(x);
            const float y0f = floorf(y);
            const float wx = x - x0f;
            const float wy = y - y0f;
            const int x0 = (int)x0f;
            const int y0 = (int)y0f;
            const int x1 = min(x0 + 1, W - 1);
            const int y1 = min(y0 + 1, W - 1);

            const float w11 = wx * wy;
            const int r0 = BASE[l] + y0 * W;
            const int r1 = BASE[l] + y1 * W;

            off[4 * s + 0] = r0 + x0;  wgt[4 * s + 0] = 1.0f - wx - wy + w11;
            off[4 * s + 1] = r0 + x1;  wgt[4 * s + 1] = wx - w11;
            off[4 * s + 2] = r1 + x0;  wgt[4 * s + 2] = wy - w11;
            off[4 * s + 3] = r1 + x1;  wgt[4 * s + 3] = w11;
        }

        // issue all 16 dwordx4 loads before consuming any
        uint4 t[16];
#pragma unroll
        for (int j = 0; j < 8; ++j) {
            const uint4* p = (const uint4*)(tex + ((size_t)off[j] << 4));
            t[2 * j]     = p[0];
            t[2 * j + 1] = p[1];
        }

#pragma unroll
        for (int j = 0; j < 8; ++j)
            accum_pair(acc, t[2 * j], t[2 * j + 1], wgt[j]);
    }

#pragma unroll
    for (int c = 0; c < NCH; ++c)
        out[(size_t)c * (IMG * IMG) + idx] = acc[c];
}

// ---------------- fallback (round-1 naive, if ws too small) ------------------
__global__ __launch_bounds__(256) void hsnt_naive(
    const float* __restrict__ uv,
    const float* __restrict__ data,
    float* __restrict__ out)
{
    const int idx = blockIdx.x * blockDim.x + threadIdx.x;
    if (idx >= IMG * IMG) return;

    const float gx = uv[idx];
    const float gy = uv[IMG * IMG + idx];

    float acc[NCH];
#pragma unroll
    for (int c = 0; c < NCH; ++c) acc[c] = 0.0f;

    int offY = 0;
    int W = 1024;
#pragma unroll
    for (int l = 0; l < 4; ++l) {
        const float Wf = (float)W;
        float x = fminf(fmaxf(fmaf(gx + 1.0f, Wf * 0.5f, -0.5f), 0.0f), Wf - 1.0f);
        float y = fminf(fmaxf(fmaf(gy + 1.0f, Wf * 0.5f, -0.5f), 0.0f), Wf - 1.0f);
        const float x0f = floorf(x);
        const float y0f = floorf(y);
        const float wx = x - x0f;
        const float wy = y - y0f;
        const int x0 = (int)x0f;
        const int y0 = (int)y0f;
        const int x1 = min(x0 + 1, W - 1);
        const int y1 = min(y0 + 1, W - 1);
        const float w11 = wx * wy;
        const float w10 = wy - w11;
        const float w01 = wx - w11;
        const float w00 = 1.0f - wx - wy + w11;
        const int r0 = offY + y0;
        const int r1 = offY + y1;
        const float* p00 = data + (size_t)r0 * DATA_ROWSTRIDE + x0;
        const float* p01 = data + (size_t)r0 * DATA_ROWSTRIDE + x1;
        const float* p10 = data + (size_t)r1 * DATA_ROWSTRIDE + x0;
        const float* p11 = data + (size_t)r1 * DATA_ROWSTRIDE + x1;
#pragma unroll
        for (int c = 0; c < NCH; ++c) {
            const size_t co = (size_t)c * DATA_CHSTRIDE;
            acc[c] = fmaf(p00[co], w00,
                     fmaf(p01[co], w01,
                     fmaf(p10[co], w10,
                     fmaf(p11[co], w11, acc[c]))));
        }
        offY += W;
        W >>= 1;
    }
#pragma unroll
    for (int c = 0; c < NCH; ++c)
        out[(size_t)c * (IMG * IMG) + idx] = acc[c];
}

extern "C" void kernel_launch(void* const* d_in, const int* in_sizes, int n_in,
                              void* d_out, int out_size, void* d_ws, size_t ws_size,
                              hipStream_t stream) {
    const float* uv   = (const float*)d_in[0];   // [1,2,1024,1024]
    const float* data = (const float*)d_in[1];   // [1,16,2048,1024]
    float* out = (float*)d_out;                  // [1,16,1024,1024]

    const int npix = IMG * IMG;
    const int block = 256;
    const int grid = (npix + block - 1) / block;

    if (ws_size >= WS_NEEDED && d_ws != nullptr) {
        __half* tex = (__half*)d_ws;
        hsnt_transpose_h<<<TOT_TEXELS / 256, 256, 0, stream>>>(data, tex);
        hsnt_sample_h<<<grid, block, 0, stream>>>(uv, tex, out);
    } else {
        hsnt_naive<<<grid, block, 0, stream>>>(uv, data, out);
    }
}